// Round 4
// baseline (88.145 us; speedup 1.0000x reference)
//
#include <hip/hip_runtime.h>
#include <math.h>

// GatingNetwork: logits = x @ W^T + b; softmax; top-2.
// Round-4 design: LDS-free, barrier-free MFMA GEMM. Round-3 was LDS-BW-bound
// (108KB LDS traffic per 64-k chunk vs ~230cyc matrix work; MfmaUtil 11%).
// Each wave: 32 tokens x 64 experts x K/4 slice, all fragments register-direct:
//   W (bf16x3 pre-split, 768KB, L2-resident) loaded per-fragment (coalesced:
//   16 rows x 64B); x loaded fp32 (16 rows x 128B) and trunc-split to bf16x3
//   in-register. 6-term Ootomo split => ~2^-24 rel error, passes like fp32.
// K-split=4 partials -> probs/mask regions + d_ws; epilogue sums + softmax/top2.

typedef __attribute__((ext_vector_type(8))) short short8;   // 8 bf16
typedef __attribute__((ext_vector_type(4))) float f32x4;

constexpr int D = 2048;
constexpr int E = 64;
constexpr int N = 16384;

__device__ inline unsigned short f2bf(float f) {            // RNE fp32->bf16
    unsigned int u = __float_as_uint(f);
    return (unsigned short)((u + 0x7fffu + ((u >> 16) & 1u)) >> 16);
}
__device__ inline float bf2f(unsigned short h) {
    return __uint_as_float(((unsigned int)h) << 16);
}

// ---- W pre-split: W fp32 [64][2048] -> w1,w2,w3 bf16 (RNE, validated r3) ----
__global__ __launch_bounds__(256) void wsplit_kernel(
    const float* __restrict__ W, unsigned short* __restrict__ w1,
    unsigned short* __restrict__ w2, unsigned short* __restrict__ w3)
{
    const int i = blockIdx.x * 256 + threadIdx.x;   // one float4 per thread
    float4 v = reinterpret_cast<const float4*>(W)[i];
    float f[4] = {v.x, v.y, v.z, v.w};
    unsigned short h1[4], h2[4], h3[4];
    #pragma unroll
    for (int j = 0; j < 4; ++j) {
        h1[j] = f2bf(f[j]);  float r  = f[j] - bf2f(h1[j]);
        h2[j] = f2bf(r);     float r2 = r    - bf2f(h2[j]);
        h3[j] = f2bf(r2);
    }
    uint2 u1 = {(unsigned)h1[0] | ((unsigned)h1[1] << 16), (unsigned)h1[2] | ((unsigned)h1[3] << 16)};
    uint2 u2 = {(unsigned)h2[0] | ((unsigned)h2[1] << 16), (unsigned)h2[2] | ((unsigned)h2[3] << 16)};
    uint2 u3 = {(unsigned)h3[0] | ((unsigned)h3[1] << 16), (unsigned)h3[2] | ((unsigned)h3[3] << 16)};
    reinterpret_cast<uint2*>(w1)[i] = u1;
    reinterpret_cast<uint2*>(w2)[i] = u2;
    reinterpret_cast<uint2*>(w3)[i] = u3;
}

// truncation split of 8 fp32 -> 3 bf16x8 fragments (exact residuals)
__device__ inline void split_frag(const float4 lo, const float4 hi,
                                  short8& a1, short8& a2, short8& a3)
{
    float f[8] = {lo.x, lo.y, lo.z, lo.w, hi.x, hi.y, hi.z, hi.w};
    #pragma unroll
    for (int j = 0; j < 8; ++j) {
        unsigned u = __float_as_uint(f[j]);
        float f1 = __uint_as_float(u & 0xffff0000u);
        a1[j] = (short)(u >> 16);
        float r = f[j] - f1;                      // exact
        unsigned u2 = __float_as_uint(r);
        float f2 = __uint_as_float(u2 & 0xffff0000u);
        a2[j] = (short)(u2 >> 16);
        float r2 = r - f2;                        // exact
        a3[j] = (short)(__float_as_uint(r2) >> 16);
    }
}

#define MFMA(A, B, C) __builtin_amdgcn_mfma_f32_16x16x32_bf16(A, B, C, 0, 0, 0)

// S = K-split factor. Wave owns 32 tokens x 64 experts x (D/S) k.
// grid = (N/128) * S blocks of 256 threads; 4 waves/block share the k-slice
// (so co-resident waves hit the same W lines in L1).
template <int S>
__global__ __launch_bounds__(256) void gating_mfma(
    const float* __restrict__ x,
    const unsigned short* __restrict__ w1, const unsigned short* __restrict__ w2,
    const unsigned short* __restrict__ w3,
    float* __restrict__ p0, float* __restrict__ p1,
    float* __restrict__ p2, float* __restrict__ p3)
{
    constexpr int KS  = D / S;      // k per wave
    constexpr int NKS = KS / 32;    // k-steps (S=4 -> 16, S=2 -> 32; both even)

    const int tid   = threadIdx.x;
    const int lane  = tid & 63;
    const int widx  = tid >> 6;
    const int fr    = lane & 15;    // token row (A) / expert row (B)
    const int fc    = lane >> 4;    // k-quarter
    const int slice = blockIdx.x % S;
    const int tgq   = blockIdx.x / S;
    const int tokBase = (tgq * 4 + widx) * 32;

    const float* xp0 = x + (size_t)(tokBase + fr) * D + slice * KS + fc * 8;
    const float* xp1 = xp0 + (size_t)16 * D;
    const size_t wo  = (size_t)fr * D + slice * KS + fc * 8;
    const unsigned short* wb[3] = {w1 + wo, w2 + wo, w3 + wo};

    float4 xr[2][2][2];     // [buf][tokgroup][half]
    short8 bw[2][12];       // [buf][m*4+g]
    f32x4  acc[2][4];       // [tokgroup][expgroup]
    #pragma unroll
    for (int t = 0; t < 2; ++t)
        #pragma unroll
        for (int g = 0; g < 4; ++g) acc[t][g] = (f32x4){0.f, 0.f, 0.f, 0.f};

#define LOADX(B, KSN)                                                          \
    xr[B][0][0] = *reinterpret_cast<const float4*>(xp0 + (KSN) * 32);          \
    xr[B][0][1] = *reinterpret_cast<const float4*>(xp0 + (KSN) * 32 + 4);      \
    xr[B][1][0] = *reinterpret_cast<const float4*>(xp1 + (KSN) * 32);          \
    xr[B][1][1] = *reinterpret_cast<const float4*>(xp1 + (KSN) * 32 + 4);

#define LOADB(B, KSN)                                                          \
    _Pragma("unroll")                                                          \
    for (int m = 0; m < 3; ++m)                                                \
        _Pragma("unroll")                                                      \
        for (int g = 0; g < 4; ++g)                                            \
            bw[B][m * 4 + g] = *reinterpret_cast<const short8*>(               \
                wb[m] + (size_t)g * 16 * D + (KSN) * 32);

#define COMPUTE(B)                                                             \
    _Pragma("unroll")                                                          \
    for (int t = 0; t < 2; ++t) {                                              \
        short8 a1, a2, a3;                                                     \
        split_frag(xr[B][t][0], xr[B][t][1], a1, a2, a3);                      \
        _Pragma("unroll")                                                      \
        for (int g = 0; g < 4; ++g) {                                          \
            acc[t][g] = MFMA(a1, bw[B][0 * 4 + g], acc[t][g]);                 \
            acc[t][g] = MFMA(a1, bw[B][1 * 4 + g], acc[t][g]);                 \
            acc[t][g] = MFMA(a2, bw[B][0 * 4 + g], acc[t][g]);                 \
            acc[t][g] = MFMA(a1, bw[B][2 * 4 + g], acc[t][g]);                 \
            acc[t][g] = MFMA(a3, bw[B][0 * 4 + g], acc[t][g]);                 \
            acc[t][g] = MFMA(a2, bw[B][1 * 4 + g], acc[t][g]);                 \
        }                                                                      \
    }

    LOADX(0, 0)
    LOADB(0, 0)
    for (int ks = 0; ks < NKS; ks += 2) {
        if (ks + 1 < NKS) { LOADX(1, ks + 1) LOADB(1, ks + 1) }
        COMPUTE(0)
        if (ks + 2 < NKS) { LOADX(0, ks + 2) LOADB(0, ks + 2) }
        COMPUTE(1)
    }

    // partial store: token = tokBase + t*16 + fc*4 + r, expert = g*16 + fr
    float* dst = (slice == 0) ? p0 : (slice == 1) ? p1 : (slice == 2) ? p2 : p3;
    #pragma unroll
    for (int t = 0; t < 2; ++t)
        #pragma unroll
        for (int g = 0; g < 4; ++g)
            #pragma unroll
            for (int r = 0; r < 4; ++r)
                dst[(size_t)(tokBase + t * 16 + fc * 4 + r) * E + g * 16 + fr] =
                    acc[t][g][r];
#undef LOADX
#undef LOADB
#undef COMPUTE
}

constexpr int BT = 64;   // tokens per epilogue block

__global__ __launch_bounds__(256) void epilogue_kernel(
    const float* __restrict__ p0, const float* __restrict__ p1,
    const float* __restrict__ p2, const float* __restrict__ p3,
    const float* __restrict__ bias, float* __restrict__ out, int split)
{
    __shared__ float lg[BT][E + 1];
    __shared__ float s_max[BT], s_rinv[BT];
    __shared__ int   s_i1[BT], s_i2[BT];

    const int tid = threadIdx.x;
    const int tokBase = blockIdx.x * BT;

    for (int f4 = tid; f4 < BT * E / 4; f4 += 256) {
        const size_t g = (size_t)tokBase * E + f4 * 4;
        float4 a = *reinterpret_cast<const float4*>(p0 + g);
        float4 b = *reinterpret_cast<const float4*>(p1 + g);
        float4 v;
        v.x = a.x + b.x; v.y = a.y + b.y; v.z = a.z + b.z; v.w = a.w + b.w;
        if (split == 4) {
            float4 c = *reinterpret_cast<const float4*>(p2 + g);
            float4 d = *reinterpret_cast<const float4*>(p3 + g);
            v.x += c.x + d.x; v.y += c.y + d.y; v.z += c.z + d.z; v.w += c.w + d.w;
        }
        const int t = (f4 * 4) >> 6;
        const int e = (f4 * 4) & 63;
        const float4 bb = *reinterpret_cast<const float4*>(bias + e);
        lg[t][e + 0] = v.x + bb.x;
        lg[t][e + 1] = v.y + bb.y;
        lg[t][e + 2] = v.z + bb.z;
        lg[t][e + 3] = v.w + bb.w;
    }
    __syncthreads();

    float* outWt = out;
    float* outIx = out + (size_t)N * 2;
    float* outMk = out + (size_t)N * 4;
    float* outPr = out + (size_t)N * 4 + (size_t)N * E;

    if (tid < BT) {
        const int t = tid;
        float m1 = -3.4e38f, m2 = -3.4e38f;
        int i1 = 0, i2 = 0;
        for (int e = 0; e < E; ++e) {
            const float l = lg[t][e];
            if (l > m1)      { m2 = m1; i2 = i1; m1 = l; i1 = e; }
            else if (l > m2) { m2 = l;  i2 = e; }
        }
        float ssum = 0.f;
        for (int e = 0; e < E; ++e) ssum += expf(lg[t][e] - m1);
        const float e2 = expf(m2 - m1);
        const float inv12 = 1.f / (1.f + e2);
        const size_t g = (size_t)(tokBase + t);
        outWt[g*2 + 0] = inv12;
        outWt[g*2 + 1] = e2 * inv12;
        outIx[g*2 + 0] = (float)i1;
        outIx[g*2 + 1] = (float)i2;
        s_max[t]  = m1;
        s_rinv[t] = 1.f / ssum;
        s_i1[t]   = i1;
        s_i2[t]   = i2;
    }
    __syncthreads();

    for (int f = tid; f < BT * E; f += 256) {
        const int t = f >> 6;
        const int e = f & 63;
        const float p = expf(lg[t][e] - s_max[t]) * s_rinv[t];
        const size_t g = (size_t)(tokBase + t) * E + e;
        outPr[g] = p;
        outMk[g] = (e == s_i1[t] || e == s_i2[t]) ? 1.0f : 0.0f;
    }
}

extern "C" void kernel_launch(void* const* d_in, const int* in_sizes, int n_in,
                              void* d_out, int out_size, void* d_ws, size_t ws_size,
                              hipStream_t stream) {
    const float* x = (const float*)d_in[0];
    const float* W = (const float*)d_in[1];
    const float* b = (const float*)d_in[2];
    float* out = (float*)d_out;

    float* outMk = out + (size_t)N * 4;
    float* outPr = out + (size_t)N * 4 + (size_t)N * E;

    unsigned short* w1 = (unsigned short*)d_ws;          // 3 x 256KB bf16 splits
    unsigned short* w2 = w1 + (size_t)E * D;
    unsigned short* w3 = w2 + (size_t)E * D;
    float* wsEnd = (float*)(w3 + (size_t)E * D);

    const size_t need4 = (size_t)3 * E * D * sizeof(unsigned short)
                       + (size_t)2 * N * E * sizeof(float);

    wsplit_kernel<<<dim3(E * D / 4 / 256), dim3(256), 0, stream>>>(W, w1, w2, w3);

    if (ws_size >= need4) {
        float* p2 = wsEnd;
        float* p3 = wsEnd + (size_t)N * E;
        gating_mfma<4><<<dim3((N / 128) * 4), dim3(256), 0, stream>>>(
            x, w1, w2, w3, outPr, outMk, p2, p3);
        epilogue_kernel<<<dim3(N / BT), dim3(256), 0, stream>>>(
            outPr, outMk, p2, p3, b, out, 4);
    } else {
        gating_mfma<2><<<dim3((N / 128) * 2), dim3(256), 0, stream>>>(
            x, w1, w2, w3, outPr, outMk, outPr, outMk);
        epilogue_kernel<<<dim3(N / BT), dim3(256), 0, stream>>>(
            outPr, outMk, outPr, outMk, b, out, 2);
    }
}

// Round 5
// 81.289 us; speedup vs baseline: 1.0843x; 1.0843x over previous
//
#include <hip/hip_runtime.h>
#include <math.h>

// GatingNetwork: logits = x @ W^T + b; softmax; top-2. Fully fused.
// bf16x3 split-MFMA (6-term Ootomo, rel err ~2^-24, validated r3/r4).
// r4 was latency-bound (8 waves/CU, compiler-collapsed pipeline; all pipes <12%).
// r5: register-direct MFMA kept, but 8-wave blocks with in-block K-split x8:
//   wave w owns 32 tok x 64 exp x k-slice [w*256, w*256+256); partials -> LDS;
//   in-block reduce + bias + softmax + top2 + all output writes. No global
//   partials, no epilogue kernel. Grid 512x512thr = 16 waves/CU (TLP >> ILP).

typedef __attribute__((ext_vector_type(8))) short short8;   // 8 bf16
typedef __attribute__((ext_vector_type(4))) float f32x4;

constexpr int D = 2048;
constexpr int E = 64;
constexpr int N = 16384;

__device__ inline unsigned short f2bf(float f) {            // RNE fp32->bf16
    unsigned int u = __float_as_uint(f);
    return (unsigned short)((u + 0x7fffu + ((u >> 16) & 1u)) >> 16);
}
__device__ inline float bf2f(unsigned short h) {
    return __uint_as_float(((unsigned int)h) << 16);
}

// ---- W pre-split: W fp32 [64][2048] -> w1,w2,w3 bf16 (validated r3/r4) ----
__global__ __launch_bounds__(256) void wsplit_kernel(
    const float* __restrict__ W, unsigned short* __restrict__ w1,
    unsigned short* __restrict__ w2, unsigned short* __restrict__ w3)
{
    const int i = blockIdx.x * 256 + threadIdx.x;   // one float4 per thread
    float4 v = reinterpret_cast<const float4*>(W)[i];
    float f[4] = {v.x, v.y, v.z, v.w};
    unsigned short h1[4], h2[4], h3[4];
    #pragma unroll
    for (int j = 0; j < 4; ++j) {
        h1[j] = f2bf(f[j]);  float r  = f[j] - bf2f(h1[j]);
        h2[j] = f2bf(r);     float r2 = r    - bf2f(h2[j]);
        h3[j] = f2bf(r2);
    }
    uint2 u1 = {(unsigned)h1[0] | ((unsigned)h1[1] << 16), (unsigned)h1[2] | ((unsigned)h1[3] << 16)};
    uint2 u2 = {(unsigned)h2[0] | ((unsigned)h2[1] << 16), (unsigned)h2[2] | ((unsigned)h2[3] << 16)};
    uint2 u3 = {(unsigned)h3[0] | ((unsigned)h3[1] << 16), (unsigned)h3[2] | ((unsigned)h3[3] << 16)};
    reinterpret_cast<uint2*>(w1)[i] = u1;
    reinterpret_cast<uint2*>(w2)[i] = u2;
    reinterpret_cast<uint2*>(w3)[i] = u3;
}

// truncation split of 8 fp32 -> 3 bf16x8 fragments (exact residuals)
__device__ inline void split_frag(const float4 lo, const float4 hi,
                                  short8& a1, short8& a2, short8& a3)
{
    float f[8] = {lo.x, lo.y, lo.z, lo.w, hi.x, hi.y, hi.z, hi.w};
    #pragma unroll
    for (int j = 0; j < 8; ++j) {
        unsigned u = __float_as_uint(f[j]);
        float f1 = __uint_as_float(u & 0xffff0000u);
        a1[j] = (short)(u >> 16);
        float r = f[j] - f1;                      // exact
        unsigned u2 = __float_as_uint(r);
        float f2 = __uint_as_float(u2 & 0xffff0000u);
        a2[j] = (short)(u2 >> 16);
        float r2 = r - f2;                        // exact
        a3[j] = (short)(__float_as_uint(r2) >> 16);
    }
}

#define MFMA(A, B, C) __builtin_amdgcn_mfma_f32_16x16x32_bf16(A, B, C, 0, 0, 0)

// 512 threads = 8 waves. Block owns 32 tokens. Wave wv: k in [wv*256, wv*256+256).
__global__ __launch_bounds__(512, 4) void gating_fused(
    const float* __restrict__ x,
    const unsigned short* __restrict__ w1, const unsigned short* __restrict__ w2,
    const unsigned short* __restrict__ w3,
    const float* __restrict__ bias, float* __restrict__ out)
{
    constexpr int NKS = 8;                  // 256 k per wave / 32
    __shared__ __align__(16) float P[8 * 32 * E];    // 64 KB: partials [wave][tok][exp]

    const int tid  = threadIdx.x;
    const int lane = tid & 63;
    const int wv   = tid >> 6;
    const int fr   = lane & 15;     // token row (A) / expert row (B)
    const int fc   = lane >> 4;     // k-quarter
    const int tokBase = blockIdx.x * 32;
    const int kOff = wv * 256;

    const float* xp0 = x + (size_t)(tokBase + fr) * D + kOff + fc * 8;
    const float* xp1 = xp0 + (size_t)16 * D;
    const size_t wo  = (size_t)fr * D + kOff + fc * 8;
    const unsigned short* wb[3] = {w1 + wo, w2 + wo, w3 + wo};

    float4 xr[2][2][2];     // [buf][tokgroup][half]
    short8 bw[2][12];       // [buf][m*4+g]
    f32x4  acc[2][4];       // [tokgroup][expgroup]
    #pragma unroll
    for (int t = 0; t < 2; ++t)
        #pragma unroll
        for (int g = 0; g < 4; ++g) acc[t][g] = (f32x4){0.f, 0.f, 0.f, 0.f};

#define LOADX(B, KSN)                                                          \
    xr[B][0][0] = *reinterpret_cast<const float4*>(xp0 + (KSN) * 32);          \
    xr[B][0][1] = *reinterpret_cast<const float4*>(xp0 + (KSN) * 32 + 4);      \
    xr[B][1][0] = *reinterpret_cast<const float4*>(xp1 + (KSN) * 32);          \
    xr[B][1][1] = *reinterpret_cast<const float4*>(xp1 + (KSN) * 32 + 4);

#define LOADB(B, KSN)                                                          \
    _Pragma("unroll")                                                          \
    for (int m = 0; m < 3; ++m)                                                \
        _Pragma("unroll")                                                      \
        for (int g = 0; g < 4; ++g)                                            \
            bw[B][m * 4 + g] = *reinterpret_cast<const short8*>(               \
                wb[m] + (size_t)g * 16 * D + (KSN) * 32);

#define COMPUTE(B)                                                             \
    _Pragma("unroll")                                                          \
    for (int t = 0; t < 2; ++t) {                                              \
        short8 a1, a2, a3;                                                     \
        split_frag(xr[B][t][0], xr[B][t][1], a1, a2, a3);                      \
        _Pragma("unroll")                                                      \
        for (int g = 0; g < 4; ++g) {                                          \
            acc[t][g] = MFMA(a1, bw[B][0 * 4 + g], acc[t][g]);                 \
            acc[t][g] = MFMA(a1, bw[B][1 * 4 + g], acc[t][g]);                 \
            acc[t][g] = MFMA(a2, bw[B][0 * 4 + g], acc[t][g]);                 \
            acc[t][g] = MFMA(a1, bw[B][2 * 4 + g], acc[t][g]);                 \
            acc[t][g] = MFMA(a3, bw[B][0 * 4 + g], acc[t][g]);                 \
            acc[t][g] = MFMA(a2, bw[B][1 * 4 + g], acc[t][g]);                 \
        }                                                                      \
    }

    LOADX(0, 0)
    LOADB(0, 0)
    #pragma unroll
    for (int ks = 0; ks < NKS; ks += 2) {
        LOADX(1, ks + 1) LOADB(1, ks + 1)
        COMPUTE(0)
        if (ks + 2 < NKS) { LOADX(0, ks + 2) LOADB(0, ks + 2) }
        COMPUTE(1)
    }
#undef LOADX
#undef LOADB
#undef COMPUTE

    // ---- partials -> LDS ----
    #pragma unroll
    for (int t = 0; t < 2; ++t)
        #pragma unroll
        for (int g = 0; g < 4; ++g)
            #pragma unroll
            for (int r = 0; r < 4; ++r)
                P[wv * (32 * E) + (t * 16 + fc * 4 + r) * E + g * 16 + fr] = acc[t][g][r];
    __syncthreads();

    // ---- reduce over 8 waves + bias (in-place into wave-0 region) ----
    {
        float4* P4 = reinterpret_cast<float4*>(P);
        const int f4 = tid;                     // 512 float4 slots = 32*64 floats
        float4 s = P4[f4];
        #pragma unroll
        for (int w = 1; w < 8; ++w) {
            float4 v = P4[w * 512 + f4];
            s.x += v.x; s.y += v.y; s.z += v.z; s.w += v.w;
        }
        const float4 bb = *reinterpret_cast<const float4*>(bias + (f4 & 15) * 4);
        s.x += bb.x; s.y += bb.y; s.z += bb.z; s.w += bb.w;
        P4[f4] = s;
    }
    __syncthreads();

    float* outWt = out;
    float* outIx = out + (size_t)N * 2;
    float* outMk = out + (size_t)N * 4;
    float* outPr = out + (size_t)N * 4 + (size_t)N * E;

    // aux arrays overlay the (consumed) wave-1 partial region
    float* s_max  = P + 2048;
    float* s_rinv = P + 2048 + 32;
    int*   s_i1   = reinterpret_cast<int*>(P + 2048 + 64);
    int*   s_i2   = reinterpret_cast<int*>(P + 2048 + 96);

    if (tid < 32) {
        const int t = tid;
        const float* lg = P + t * E;
        float m1 = -3.4e38f, m2 = -3.4e38f;
        int i1 = 0, i2 = 0;
        for (int e = 0; e < E; ++e) {
            const float l = lg[e];
            if (l > m1)      { m2 = m1; i2 = i1; m1 = l; i1 = e; }
            else if (l > m2) { m2 = l;  i2 = e; }
        }
        float ssum = 0.f;
        for (int e = 0; e < E; ++e) ssum += expf(lg[e] - m1);
        const float e2 = expf(m2 - m1);
        const float inv12 = 1.f / (1.f + e2);
        const size_t g = (size_t)(tokBase + t);
        outWt[g * 2 + 0] = inv12;
        outWt[g * 2 + 1] = e2 * inv12;
        outIx[g * 2 + 0] = (float)i1;
        outIx[g * 2 + 1] = (float)i2;
        s_max[t]  = m1;
        s_rinv[t] = 1.f / ssum;
        s_i1[t]   = i1;
        s_i2[t]   = i2;
    }
    __syncthreads();

    for (int f = tid; f < 32 * E; f += 512) {
        const int t = f >> 6;
        const int e = f & 63;
        const float p = expf(P[t * E + e] - s_max[t]) * s_rinv[t];
        const size_t g = (size_t)(tokBase + t) * E + e;
        outPr[g] = p;
        outMk[g] = (e == s_i1[t] || e == s_i2[t]) ? 1.0f : 0.0f;
    }
}

extern "C" void kernel_launch(void* const* d_in, const int* in_sizes, int n_in,
                              void* d_out, int out_size, void* d_ws, size_t ws_size,
                              hipStream_t stream) {
    const float* x = (const float*)d_in[0];
    const float* W = (const float*)d_in[1];
    const float* b = (const float*)d_in[2];
    float* out = (float*)d_out;

    unsigned short* w1 = (unsigned short*)d_ws;          // 3 x 256KB bf16 splits
    unsigned short* w2 = w1 + (size_t)E * D;
    unsigned short* w3 = w2 + (size_t)E * D;

    wsplit_kernel<<<dim3(E * D / 4 / 256), dim3(256), 0, stream>>>(W, w1, w2, w3);
    gating_fused<<<dim3(N / 32), dim3(512), 0, stream>>>(x, w1, w2, w3, b, out);
}